// Round 8
// baseline (608.905 us; speedup 1.0000x reference)
//
#include <hip/hip_runtime.h>
#include <hip/hip_bf16.h>

#define DIM   512
#define QKVD  1536
#define HEADS 8
#define HD    64
#define NSEQ  4096
#define LDP   72    // padded stride for transpose staging (144B, conflict-free)
#define LDPK  72
#define LDPV  136   // 272B stride, conflict-free b128
#define SCALE_LOG2E 0.18033688011112042f   // 0.125 * log2(e), folded into Q

typedef float  f32x4  __attribute__((ext_vector_type(4)));
typedef __bf16 bf16x8 __attribute__((ext_vector_type(8)));
typedef __bf16 bf16x4 __attribute__((ext_vector_type(4)));
typedef short  s16x4  __attribute__((ext_vector_type(4)));

static __device__ inline f32x4 mfma32(bf16x8 a, bf16x8 b, f32x4 c) {
  return __builtin_amdgcn_mfma_f32_16x16x32_bf16(a, b, c, 0, 0, 0);
}
static __device__ inline s16x4 pack_bf16(f32x4 v) {
  bf16x4 b = __builtin_convertvector(v, bf16x4);
  return __builtin_bit_cast(s16x4, b);
}
// async global->LDS DMA, 16B per lane; LDS dest = wave-uniform base + lane*16.
static __device__ inline void gl_lds16(const __bf16* g, __bf16* l) {
  __builtin_amdgcn_global_load_lds(
      (const __attribute__((address_space(1))) unsigned int*)g,
      (__attribute__((address_space(3))) unsigned int*)l, 16, 0, 0);
}

// One fused conversion pass: x (1048576 vec4) + qkv_w (196608) + proj_w (65536)
// = 1310720 vec4 = 5120 blocks x 256 threads exactly.
__global__ __launch_bounds__(256) void cvt_all(const float* __restrict__ x,
                                               const float* __restrict__ qkv_w,
                                               const float* __restrict__ proj_w,
                                               __bf16* __restrict__ xb,
                                               __bf16* __restrict__ wqkv,
                                               __bf16* __restrict__ wproj) {
  int i = blockIdx.x * 256 + threadIdx.x;
  const float* s; __bf16* d; int off;
  if (i < 1048576)                 { s = x;      d = xb;    off = i; }
  else if (i < 1048576 + 196608)   { s = qkv_w;  d = wqkv;  off = i - 1048576; }
  else                             { s = proj_w; d = wproj; off = i - 1245184; }
  f32x4 v = ((const f32x4*)s)[off];
  *(bf16x4*)(d + 4 * (size_t)off) = __builtin_convertvector(v, bf16x4);
}

// 128x128-tile GEMM, global_load_lds staging (linear [row][64] LDS):
// nt 0..7:  C[m][oc] = A * Bw^T + bias  (Q cols scaled by 0.125*log2e)
// nt 8..11: V columns transposed in-block (transpose_v's exact pattern +
//           key permutation) and stored directly to Vt[bh][d][perm(n)].
// NOTE (r6): the pass loop MUST be fully unrolled -- a runtime `pass` index
// into acc[][] sends the whole accumulator to scratch (rule #20).
__global__ __launch_bounds__(256) void gemm_qkv(const __bf16* __restrict__ A,
                                                const __bf16* __restrict__ Bw,
                                                const float* __restrict__ bias,
                                                __bf16* __restrict__ C,
                                                __bf16* __restrict__ Vt) {
  const int mt = blockIdx.x;   // 0..63
  const int nt = blockIdx.y;   // 0..11
  __shared__ __bf16 S[2 * 128 * 64];   // 32 KB: As | Bs; reused as T[128][72]
  __bf16* As = S;
  __bf16* Bs = S + 128 * 64;
  const int tid = threadIdx.x, w = tid >> 6, lane = tid & 63;
  const int l16 = lane & 15, quad = lane >> 4;
  const int ch0 = w << 2;
  const int lrow = lane >> 3, lcol = (lane & 7) << 3;

  f32x4 acc[2][8] = {};
  for (int kt = 0; kt < 8; ++kt) {
    __syncthreads();
    const __bf16* Ak = A + (size_t)(mt * 128) * DIM + kt * 64;
    const __bf16* Bk = Bw + (size_t)(nt * 128) * DIM + kt * 64;
#pragma unroll
    for (int i = 0; i < 4; ++i) {
      int ch = ch0 + i;
      gl_lds16(Ak + (size_t)(ch * 8 + lrow) * DIM + lcol, As + ch * 512);
      gl_lds16(Bk + (size_t)(ch * 8 + lrow) * DIM + lcol, Bs + ch * 512);
    }
    __syncthreads();
#pragma unroll
    for (int c = 0; c < 2; ++c) {
      bf16x8 a[2];
#pragma unroll
      for (int mtt = 0; mtt < 2; ++mtt)
        a[mtt] = *(const bf16x8*)(As + (w * 32 + mtt * 16 + l16) * 64 + quad * 8 + c * 32);
#pragma unroll
      for (int ct = 0; ct < 8; ++ct) {
        bf16x8 bb = *(const bf16x8*)(Bs + (ct * 16 + l16) * 64 + quad * 8 + c * 32);
#pragma unroll
        for (int mtt = 0; mtt < 2; ++mtt)
          acc[mtt][ct] = mfma32(a[mtt], bb, acc[mtt][ct]);
      }
    }
  }

  if (nt < 8) {
    const float sc = (nt < 4) ? SCALE_LOG2E : 1.0f;   // nt 0..3 = Q columns
#pragma unroll
    for (int ct = 0; ct < 8; ++ct) {
      int oc = nt * 128 + ct * 16 + l16;
      float bv = bias[oc];
#pragma unroll
      for (int mtt = 0; mtt < 2; ++mtt)
#pragma unroll
        for (int r = 0; r < 4; ++r) {
          int mrow = mt * 128 + w * 32 + mtt * 16 + quad * 4 + r;
          C[(size_t)mrow * QKVD + oc] = (__bf16)((acc[mtt][ct][r] + bv) * sc);
        }
    }
  } else {
    __bf16* T = S;   // 128*72*2 = 18432 B <= 32768 B
#pragma unroll
    for (int pass = 0; pass < 2; ++pass) {   // FULLY unrolled: acc idx static
      __syncthreads();
#pragma unroll
      for (int ct4 = 0; ct4 < 4; ++ct4) {
        int ct = pass * 4 + ct4;
        int oc = nt * 128 + ct * 16 + l16;
        float bv = bias[oc];
        int col = ct4 * 16 + l16;   // 0..63 within head
#pragma unroll
        for (int mtt = 0; mtt < 2; ++mtt)
#pragma unroll
          for (int r = 0; r < 4; ++r) {
            int rowl = w * 32 + mtt * 16 + quad * 4 + r;   // 0..127
            T[rowl * LDP + col] = (__bf16)(acc[mtt][ct][r] + bv);
          }
      }
      __syncthreads();
      const int h = (nt - 8) * 2 + pass;
      const int d = tid >> 2, t = tid & 3;
      const int g2 = t >> 1, m2 = t & 1;
#pragma unroll
      for (int sub = 0; sub < 2; ++sub) {
        int mrow0 = mt * 128 + sub * 64;
        int b = mrow0 >> 12;
        int n64 = (mrow0 & 4095) >> 6;
        __bf16* dst = Vt + ((size_t)(b * 8 + h) * HD + d) * NSEQ +
                      n64 * 64 + g2 * 32 + m2 * 4;
#pragma unroll
        for (int u = 0; u < 4; ++u) {
          bf16x4 o;
#pragma unroll
          for (int jj = 0; jj < 4; ++jj)
            o[jj] = T[(sub * 64 + t * 16 + u * 4 + jj) * LDP + d];
          *(bf16x4*)(dst + u * 8) = o;
        }
      }
    }
  }
}

// 128x64-tile GEMM, global_load_lds staging, fp32 output:
// out = A[8192x512] * Bw[512x512]^T + bias.
__global__ __launch_bounds__(256) void gemm_proj(const __bf16* __restrict__ A,
                                                 const __bf16* __restrict__ Bw,
                                                 const float* __restrict__ bias,
                                                 float* __restrict__ C) {
  const int mt = blockIdx.x;   // 0..63
  const int nt = blockIdx.y;   // 0..7
  __shared__ __bf16 As[128 * 64];
  __shared__ __bf16 Bs[64 * 64];
  const int tid = threadIdx.x, w = tid >> 6, lane = tid & 63;
  const int l16 = lane & 15, quad = lane >> 4;
  const int lrow = lane >> 3, lcol = (lane & 7) << 3;
  const int cha0 = w << 2;
  const int chb0 = w << 1;

  f32x4 acc[2][4] = {};
  for (int kt = 0; kt < 8; ++kt) {
    __syncthreads();
    const __bf16* Ak = A + (size_t)(mt * 128) * DIM + kt * 64;
    const __bf16* Bk = Bw + (size_t)(nt * 64) * DIM + kt * 64;
#pragma unroll
    for (int i = 0; i < 4; ++i) {
      int ch = cha0 + i;
      gl_lds16(Ak + (size_t)(ch * 8 + lrow) * DIM + lcol, As + ch * 512);
    }
#pragma unroll
    for (int i = 0; i < 2; ++i) {
      int ch = chb0 + i;
      gl_lds16(Bk + (size_t)(ch * 8 + lrow) * DIM + lcol, Bs + ch * 512);
    }
    __syncthreads();
#pragma unroll
    for (int c = 0; c < 2; ++c) {
      bf16x8 a[2];
#pragma unroll
      for (int mtt = 0; mtt < 2; ++mtt)
        a[mtt] = *(const bf16x8*)(As + (w * 32 + mtt * 16 + l16) * 64 + quad * 8 + c * 32);
#pragma unroll
      for (int ct = 0; ct < 4; ++ct) {
        bf16x8 bb = *(const bf16x8*)(Bs + (ct * 16 + l16) * 64 + quad * 8 + c * 32);
#pragma unroll
        for (int mtt = 0; mtt < 2; ++mtt)
          acc[mtt][ct] = mfma32(a[mtt], bb, acc[mtt][ct]);
      }
    }
  }
#pragma unroll
  for (int ct = 0; ct < 4; ++ct) {
    int oc = nt * 64 + ct * 16 + l16;
    float bv = bias[oc];
#pragma unroll
    for (int mtt = 0; mtt < 2; ++mtt)
#pragma unroll
      for (int r = 0; r < 4; ++r) {
        int mrow = mt * 128 + w * 32 + mtt * 16 + quad * 4 + r;
        C[(size_t)mrow * DIM + oc] = acc[mtt][ct][r] + bv;
      }
  }
}

// Flash attention v12: v7 inner loop VERBATIM (mt=4, two 4-wave groups),
// key range split across blockIdx.z (G=0/1, 2048 keys each; 1024/group,
// 8 kt). Grid 16x16x2 = 512 blocks; VGPR<=128 (launch_bounds(512,4)) and
// LDS 81920x2 = exactly 160 KiB -> 2 blocks/CU = 4 waves/SIMD (v7: 2).
// Per-wave per-kt cost and total LDS traffic identical to v7 (r1's mt-halving
// and r3's 1024-thread reg-cap failure modes both avoided).
// Output: unnormalized f32 partial (O cols 0..63, l at col 64; record = 68
// f32) per (G,bh,row); combine_o sums G partials and normalizes.
// NOTE (r4): no s_setprio here -- measured -20% on this lockstep structure.
__global__ __launch_bounds__(512, 4) void attn_fused(const __bf16* __restrict__ QKV,
                                                     const __bf16* __restrict__ Vtp,
                                                     float* __restrict__ Pw) {
  const int qt = blockIdx.x;   // 0..15 (256 q rows)
  const int bh = blockIdx.y;   // 0..15
  const int G  = blockIdx.z;   // 0..1 (key half)
  const int b = bh >> 3, h = bh & 7;

  __shared__ __align__(16) char smem[81920];
  __bf16* KsAll  = (__bf16*)smem;               // [2][128*LDPK] = 36864 B
  __bf16* VtsAll = (__bf16*)(smem + 36864);     // [2][64*LDPV]  = 34816 B
  float*  Oex    = (float*)smem;                // 81920 B (after compute)

  const int tid = threadIdx.x, w = tid >> 6, lane = tid & 63;
  const int wg = w & 3, grp = w >> 2;
  const int l16 = lane & 15, quad = lane >> 4;
  const int g256 = tid & 255;

  __bf16* Ks  = KsAll + grp * (128 * LDPK);
  __bf16* Vts = VtsAll + grp * (64 * LDPV);

  const __bf16* Qb = QKV + (size_t)(b * NSEQ + qt * 256) * QKVD + h * 64;
  const __bf16* Kb = QKV + ((size_t)b * NSEQ + (size_t)(G * 2048 + grp * 1024)) * QKVD + 512 + h * 64;
  const __bf16* Vp = Vtp + (size_t)bh * HD * NSEQ + G * 2048 + grp * 1024;

  // Q fragments (one-time); both groups load the same rows
  bf16x8 aq[4][2];
#pragma unroll
  for (int mt = 0; mt < 4; ++mt)
#pragma unroll
    for (int c = 0; c < 2; ++c)
      aq[mt][c] = *(const bf16x8*)(Qb + (size_t)(wg * 64 + mt * 16 + l16) * QKVD +
                                   quad * 8 + c * 32);

  int krow[4], kc8[4], vd[4], vp8[4];
#pragma unroll
  for (int i = 0; i < 4; ++i) {
    int ch = g256 + i * 256;
    krow[i] = ch >> 3; kc8[i] = (ch & 7) << 3;
    vd[i] = ch >> 4;   vp8[i] = (ch & 15) << 3;
  }

  bf16x8 kreg[4], vreg[4];
#pragma unroll
  for (int i = 0; i < 4; ++i) {
    kreg[i] = *(const bf16x8*)(Kb + (size_t)krow[i] * QKVD + kc8[i]);
    vreg[i] = *(const bf16x8*)(Vp + (size_t)vd[i] * NSEQ + vp8[i]);
  }

  bf16x8 ones;
#pragma unroll
  for (int j = 0; j < 8; ++j) ones[j] = (__bf16)1.0f;

  f32x4 Oacc[4][5] = {};   // dt 0..3 = O, dt 4 = l (ones-column)

  for (int kt = 0; kt < 8; ++kt) {
    __syncthreads();
#pragma unroll
    for (int i = 0; i < 4; ++i) {
      *(bf16x8*)(Ks + krow[i] * LDPK + kc8[i]) = kreg[i];
      *(bf16x8*)(Vts + vd[i] * LDPV + vp8[i]) = vreg[i];
    }
    __syncthreads();

    if (kt + 1 < 8) {
      const __bf16* Kn = Kb + (size_t)(kt + 1) * 128 * QKVD;
      const __bf16* Vn = Vp + (size_t)(kt + 1) * 128;
#pragma unroll
      for (int i = 0; i < 4; ++i) {
        kreg[i] = *(const bf16x8*)(Kn + (size_t)krow[i] * QKVD + kc8[i]);
        vreg[i] = *(const bf16x8*)(Vn + (size_t)vd[i] * NSEQ + vp8[i]);
      }
    }

#pragma unroll
    for (int g = 0; g < 4; ++g) {
      bf16x8 kb[2][2];
#pragma unroll
      for (int e = 0; e < 2; ++e)
#pragma unroll
        for (int c = 0; c < 2; ++c)
          kb[e][c] = *(const bf16x8*)(Ks + ((2 * g + e) * 16 + l16) * LDPK +
                                      quad * 8 + c * 32);
      bf16x8 ap[4];
#pragma unroll
      for (int mt = 0; mt < 4; ++mt) {
        f32x4 a0 = {}, a1 = {};
        a0 = mfma32(kb[0][0], aq[mt][0], a0);
        a0 = mfma32(kb[0][1], aq[mt][1], a0);
        a1 = mfma32(kb[1][0], aq[mt][0], a1);
        a1 = mfma32(kb[1][1], aq[mt][1], a1);
        f32x4 e0, e1;
#pragma unroll
        for (int r = 0; r < 4; ++r) {
          e0[r] = __builtin_amdgcn_exp2f(a0[r]);
          e1[r] = __builtin_amdgcn_exp2f(a1[r]);
        }
        ap[mt] = __builtin_bit_cast(bf16x8,
            __builtin_shufflevector(pack_bf16(e0), pack_bf16(e1), 0, 1, 2, 3, 4, 5, 6, 7));
      }
#pragma unroll
      for (int dt = 0; dt < 4; ++dt) {
        bf16x8 bv = *(const bf16x8*)(Vts + (dt * 16 + l16) * LDPV + g * 32 + quad * 8);
#pragma unroll
        for (int mt = 0; mt < 4; ++mt)
          Oacc[mt][dt] = mfma32(ap[mt], bv, Oacc[mt][dt]);
      }
#pragma unroll
      for (int mt = 0; mt < 4; ++mt)
        Oacc[mt][4] = mfma32(ap[mt], ones, Oacc[mt][4]);   // l column
    }
  }

  // in-block combine grp1 -> grp0 via LDS, then grp0 writes the G-partial
  __syncthreads();
  if (grp == 1) {
#pragma unroll
    for (int mt = 0; mt < 4; ++mt)
#pragma unroll
      for (int dt = 0; dt < 5; ++dt)
        *(f32x4*)(Oex + (((wg * 4 + mt) * 5 + dt) << 8) + (lane << 2)) = Oacc[mt][dt];
  }
  __syncthreads();
  if (grp == 0) {
    float* rec_base = Pw + (size_t)(G * 16 + bh) * 4096 * 68;
#pragma unroll
    for (int mt = 0; mt < 4; ++mt) {
#pragma unroll
      for (int dt = 0; dt < 5; ++dt)
        Oacc[mt][dt] += *(const f32x4*)(Oex + (((wg * 4 + mt) * 5 + dt) << 8) + (lane << 2));
#pragma unroll
      for (int r = 0; r < 4; ++r) {
        int nn = qt * 256 + wg * 64 + mt * 16 + quad * 4 + r;   // 0..4095
        float* rec = rec_base + (size_t)nn * 68;
#pragma unroll
        for (int dt = 0; dt < 4; ++dt)
          rec[dt * 16 + l16] = Oacc[mt][dt][r];
        if (l16 == 0) rec[64] = Oacc[mt][4][r];   // all l16 hold the same l
      }
    }
  }
}

// Sum the two G-partials and normalize: Ob[b*4096+nn][h*64+d] bf16.
// 16 bh x 4096 nn x 16 dv = 1,048,576 threads = 4096 blocks x 256.
__global__ __launch_bounds__(256) void combine_o(const float* __restrict__ Pw,
                                                 __bf16* __restrict__ Ob) {
  int gid = blockIdx.x * 256 + threadIdx.x;
  int bh = gid >> 16, rem = gid & 65535, nn = rem >> 4, dv = rem & 15;
  const float* r0 = Pw + ((size_t)bh * 4096 + nn) * 68;
  const float* r1 = r0 + (size_t)16 * 4096 * 68;
  f32x4 o0 = *(const f32x4*)(r0 + dv * 4);
  f32x4 o1 = *(const f32x4*)(r1 + dv * 4);
  float inv = 1.0f / (r0[64] + r1[64]);
  int b = bh >> 3, h = bh & 7;
  bf16x4 ob;
#pragma unroll
  for (int j = 0; j < 4; ++j) ob[j] = (__bf16)((o0[j] + o1[j]) * inv);
  *(bf16x4*)(Ob + (size_t)(b * 4096 + nn) * DIM + h * 64 + dv * 4) = ob;
}

extern "C" void kernel_launch(void* const* d_in, const int* in_sizes, int n_in,
                              void* d_out, int out_size, void* d_ws, size_t ws_size,
                              hipStream_t stream) {
  const float* x      = (const float*)d_in[0];   // [2,4096,512]
  const float* qkv_w  = (const float*)d_in[1];   // [1536,512]
  const float* qkv_b  = (const float*)d_in[2];   // [1536]
  const float* proj_w = (const float*)d_in[3];   // [512,512]
  const float* proj_b = (const float*)d_in[4];   // [512]
  float* out = (float*)d_out;                    // [2,4096,512] fp32

  char* ws = (char*)d_ws;
  // Lifetime-based layout (68 MB total):
  //   [0, 8M)      Vtw   : written gemm_qkv, read attn;   DEAD after attn
  //                Ob    : aliases Vtw; written combine_o, read gemm_proj
  //   [8M, 32M)    qkvC  : written gemm_qkv, read attn (V third unused)
  //   [32M, ..)    wqkv (1.5M), wproj (0.5M)
  //   [34M, 42M)   xb    : written cvt_all, read gemm_qkv; DEAD after
  //   [34M, 68M)   Pw    : partials [2G][16bh][4096][68 f32]; aliases xb
  //                (attn writes Pw only after gemm_qkv is complete)
  __bf16* Vtw   = (__bf16*)(ws);                 // 8,388,608 B
  __bf16* qkvC  = (__bf16*)(ws + 8388608);       // 25,165,824 B
  __bf16* wqkv  = (__bf16*)(ws + 33554432);      // 1,572,864 B
  __bf16* wproj = (__bf16*)(ws + 35127296);      // 524,288 B
  __bf16* xb    = (__bf16*)(ws + 35651584);      // 8,388,608 B (dead after gemm_qkv)
  float*  Pw    = (float*) (ws + 35651584);      // 35,651,584 B (aliases xb)
  __bf16* Ob    = (__bf16*)(ws);                 // aliases Vtw (dead after attn)
  // total = 35,651,584 + 35,651,584 = 71,303,168 B

  cvt_all<<<5120, 256, 0, stream>>>(x, qkv_w, proj_w, xb, wqkv, wproj);
  gemm_qkv<<<dim3(64, 12), 256, 0, stream>>>(xb, wqkv, qkv_b, qkvC, Vtw);
  attn_fused<<<dim3(16, 16, 2), 512, 0, stream>>>(qkvC, Vtw, Pw);
  combine_o<<<4096, 256, 0, stream>>>(Pw, Ob);
  gemm_proj<<<dim3(64, 8), 256, 0, stream>>>(Ob, wproj, proj_b, out);
}